// Round 1
// baseline (628.725 us; speedup 1.0000x reference)
//
#include <hip/hip_runtime.h>
#include <cmath>

// Problem constants: B=1024, IN=1024, OUT=1024, K=100
#define KSAMP 100
#define DIN   1024
#define DOUT  1024
#define DB    1024

typedef float f4 __attribute__((ext_vector_type(4)));

// ---------------------------------------------------------------------------
// Kernel 1: W_eff[i][j] = mean_k(eps[k][i][j]) * softplus(ws[i][j]) + wm[i][j]
// Pure HBM stream of eps (419 MB). One float4 per thread, marches k.
// Also zeroes the 64 per-tile arrival counters used by the fused GEMM reduce.
// ---------------------------------------------------------------------------
__global__ __launch_bounds__(256) void weff_kernel(
    const f4* __restrict__ eps,
    const f4* __restrict__ wm,
    const f4* __restrict__ ws,
    f4* __restrict__ weff,
    int* __restrict__ counters)
{
    const int idx = blockIdx.x * blockDim.x + threadIdx.x;   // 0..262143
    const int n4 = (DIN * DOUT) / 4;

    if (blockIdx.x == 0 && threadIdx.x < 64) counters[threadIdx.x] = 0;

    // Hoist the small operands so their latency hides under the eps stream
    f4 s = ws[idx];
    f4 m = wm[idx];

    f4 acc0 = {0.f, 0.f, 0.f, 0.f};
    f4 acc1 = {0.f, 0.f, 0.f, 0.f};
    const f4* p = eps + idx;
    // 100 = 50 x 2; deep unroll -> many loads in flight, two acc chains
    #pragma unroll 10
    for (int k = 0; k < KSAMP; k += 2) {
        f4 e0 = __builtin_nontemporal_load(p);
        f4 e1 = __builtin_nontemporal_load(p + n4);
        p += 2 * n4;
        acc0 += e0;
        acc1 += e1;
    }
    f4 sum = acc0 + acc1;
    const float invK = 1.0f / (float)KSAMP;

    // softplus(v) = max(v,0) + log1p(exp(-|v|))  (numerically stable)
    f4 sp;
    sp.x = fmaxf(s.x, 0.f) + log1pf(expf(-fabsf(s.x)));
    sp.y = fmaxf(s.y, 0.f) + log1pf(expf(-fabsf(s.y)));
    sp.z = fmaxf(s.z, 0.f) + log1pf(expf(-fabsf(s.z)));
    sp.w = fmaxf(s.w, 0.f) + log1pf(expf(-fabsf(s.w)));

    f4 o;
    o.x = fmaf(sum.x * invK, sp.x, m.x);
    o.y = fmaf(sum.y * invK, sp.y, m.y);
    o.z = fmaf(sum.z * invK, sp.z, m.z);
    o.w = fmaf(sum.w * invK, sp.w, m.w);
    weff[idx] = o;
}

// ---------------------------------------------------------------------------
// Kernel 2: split-K fp32 GEMM with fused final reduction.
// 128x128 tile, 256 threads, 8x8 micro-tile, BK=16, KSPLIT=8 -> 512 blocks
// (2 blocks/CU). BK=16 halves the barrier count vs BK=8. B fragments use
// split-column mapping {tx*4, 64+tx*4} so Bs reads are 16B-stride across
// lanes (2-way bank aliasing = free) instead of 32B-stride (4-way conflict).
// The last kz-block to finish each (bx,by) tile sums all 8 partials and
// writes d_out directly (release fence -> atomic arrival -> acquire fence),
// eliminating the separate reduce dispatch.
// ---------------------------------------------------------------------------
#define BM 128
#define BN 128
#define BK 16
#define KSPLIT 8

__global__ __launch_bounds__(256, 2) void sgemm_splitk_fused(
    const float* __restrict__ A,   // x      [DB,  DIN]
    const float* __restrict__ B,   // W_eff  [DIN, DOUT]
    float* __restrict__ P,         // partials [KSPLIT][DB][DOUT]
    int* __restrict__ counters,    // [64] per-tile arrival counts (pre-zeroed)
    float* __restrict__ Out)       // [DB][DOUT]
{
    __shared__ float As[BK][BM];   // k-major (A transposed in LDS)
    __shared__ float Bs[BK][BN];

    const int bx = blockIdx.x, by = blockIdx.y, kz = blockIdx.z;
    const int tid = threadIdx.x;
    const int tx = tid & 15;       // 0..15 -> cols {tx*4..+3} and {64+tx*4..+3}
    const int ty = tid >> 4;       // 0..15 -> 8 output rows each

    const int kc = DIN / KSPLIT;   // 128
    const int k_begin = kz * kc;

    // A load map: row = tid>>1 (0..127), kcol = (tid&1)*8, two float4 each
    const int arow = tid >> 1;
    const int acol = (tid & 1) * 8;
    // B load map: krow = tid>>5 (0..7) and krow+8, col = (tid&31)*4
    const int brow = tid >> 5;
    const int bcol = (tid & 31) * 4;

    const float* Aptr = &A[(size_t)(by * BM + arow) * DIN + k_begin + acol];
    const float* Bptr = &B[(size_t)(k_begin + brow) * DOUT + bx * BN + bcol];

    float acc[8][8];
    #pragma unroll
    for (int i = 0; i < 8; ++i)
        #pragma unroll
        for (int j = 0; j < 8; ++j) acc[i][j] = 0.f;

    // Preload first tile
    float4 a0 = *(const float4*)Aptr;
    float4 a1 = *(const float4*)(Aptr + 4);
    float4 b0 = *(const float4*)Bptr;
    float4 b1 = *(const float4*)(Bptr + 8 * DOUT);

    const int niter = kc / BK;     // 8
    for (int it = 0; it < niter; ++it) {
        __syncthreads();           // previous iteration's LDS reads done
        As[acol + 0][arow] = a0.x;
        As[acol + 1][arow] = a0.y;
        As[acol + 2][arow] = a0.z;
        As[acol + 3][arow] = a0.w;
        As[acol + 4][arow] = a1.x;
        As[acol + 5][arow] = a1.y;
        As[acol + 6][arow] = a1.z;
        As[acol + 7][arow] = a1.w;
        *(float4*)&Bs[brow][bcol]     = b0;
        *(float4*)&Bs[brow + 8][bcol] = b1;
        __syncthreads();           // tile visible

        // Prefetch next tile while computing this one (hides ~900cyc HBM/L2)
        if (it + 1 < niter) {
            a0 = *(const float4*)(Aptr + (it + 1) * BK);
            a1 = *(const float4*)(Aptr + (it + 1) * BK + 4);
            b0 = *(const float4*)(Bptr + (size_t)((it + 1) * BK) * DOUT);
            b1 = *(const float4*)(Bptr + (size_t)((it + 1) * BK + 8) * DOUT);
        }

        #pragma unroll
        for (int kk = 0; kk < BK; ++kk) {
            float4 A0 = *(const float4*)&As[kk][ty * 8];
            float4 A1 = *(const float4*)&As[kk][ty * 8 + 4];
            float4 B0 = *(const float4*)&Bs[kk][tx * 4];        // 16B lane stride
            float4 B1 = *(const float4*)&Bs[kk][64 + tx * 4];   // conflict-free
            const float ar[8] = {A0.x, A0.y, A0.z, A0.w, A1.x, A1.y, A1.z, A1.w};
            const float br[8] = {B0.x, B0.y, B0.z, B0.w, B1.x, B1.y, B1.z, B1.w};
            #pragma unroll
            for (int i = 0; i < 8; ++i)
                #pragma unroll
                for (int j = 0; j < 8; ++j)
                    acc[i][j] = fmaf(ar[i], br[j], acc[i][j]);
        }
    }

    // Store this split's partials (split-column layout matches acc mapping)
    float* Pz = P + (size_t)kz * DB * DOUT;
    #pragma unroll
    for (int i = 0; i < 8; ++i) {
        const int r = by * BM + ty * 8 + i;
        float* prow = &Pz[(size_t)r * DOUT + bx * BN];
        *(f4*)&prow[tx * 4]      = (f4){acc[i][0], acc[i][1], acc[i][2], acc[i][3]};
        *(f4*)&prow[64 + tx * 4] = (f4){acc[i][4], acc[i][5], acc[i][6], acc[i][7]};
    }

    // Last block for this (bx,by) tile sums the KSPLIT partials -> Out
    __threadfence();                               // release: partials visible
    __shared__ int isLast;
    if (tid == 0) {
        int prev = atomicAdd(&counters[by * 8 + bx], 1);
        isLast = (prev == KSPLIT - 1) ? 1 : 0;
    }
    __syncthreads();
    if (isLast) {
        __threadfence();                           // acquire: see all partials
        #pragma unroll
        for (int i = 0; i < 8; ++i) {
            const int r = by * BM + ty * 8 + i;
            const size_t rowoff = (size_t)r * DOUT + bx * BN;
            f4 s0 = {0.f, 0.f, 0.f, 0.f};
            f4 s1 = {0.f, 0.f, 0.f, 0.f};
            #pragma unroll
            for (int z = 0; z < KSPLIT; ++z) {
                const float* pz = P + (size_t)z * DB * DOUT + rowoff;
                s0 += *(const f4*)&pz[tx * 4];
                s1 += *(const f4*)&pz[64 + tx * 4];
            }
            *(f4*)&Out[rowoff + tx * 4]      = s0;
            *(f4*)&Out[rowoff + 64 + tx * 4] = s1;
        }
    }
}

// ---------------------------------------------------------------------------
extern "C" void kernel_launch(void* const* d_in, const int* in_sizes, int n_in,
                              void* d_out, int out_size, void* d_ws, size_t ws_size,
                              hipStream_t stream) {
    const float* x   = (const float*)d_in[0];   // [1024,1024]
    const float* eps = (const float*)d_in[1];   // [100,1024,1024]
    const float* wm  = (const float*)d_in[2];   // [1024,1024]
    const float* ws  = (const float*)d_in[3];   // [1024,1024]

    float* weff     = (float*)d_ws;                                  // 4 MB
    float* partials = (float*)d_ws + (size_t)DIN * DOUT;             // 8 x 4 MB
    int*   counters = (int*)((float*)d_ws + (size_t)DIN * DOUT
                             + (size_t)KSPLIT * DB * DOUT);          // 64 ints

    weff_kernel<<<(DIN * DOUT / 4) / 256, 256, 0, stream>>>(
        (const f4*)eps, (const f4*)wm, (const f4*)ws, (f4*)weff, counters);

    sgemm_splitk_fused<<<dim3(DOUT / BN, DB / BM, KSPLIT), 256, 0, stream>>>(
        x, weff, partials, counters, (float*)d_out);
}

// Round 2
// 584.915 us; speedup vs baseline: 1.0749x; 1.0749x over previous
//
#include <hip/hip_runtime.h>
#include <cmath>

// Problem constants: B=1024, IN=1024, OUT=1024, K=100
#define KSAMP 100
#define DIN   1024
#define DOUT  1024
#define DB    1024

typedef float f4 __attribute__((ext_vector_type(4)));  // native vec for nontemporal

// ---------------------------------------------------------------------------
// Kernel 1: W_eff[i][j] = mean_k(eps[k][i][j]) * softplus(ws[i][j]) + wm[i][j]
// Pure HBM stream of eps (419 MB). One float4 per thread, marches k.
// ---------------------------------------------------------------------------
__global__ __launch_bounds__(256) void weff_kernel(
    const f4* __restrict__ eps,
    const f4* __restrict__ wm,
    const f4* __restrict__ ws,
    f4* __restrict__ weff)
{
    const int idx = blockIdx.x * blockDim.x + threadIdx.x;   // 0..262143
    const int n4 = (DIN * DOUT) / 4;

    f4 acc0 = {0.f, 0.f, 0.f, 0.f};
    f4 acc1 = {0.f, 0.f, 0.f, 0.f};
    const f4* p = eps + idx;
    // 100 = 50 x 2; deep unroll -> many loads in flight, two acc chains
    #pragma unroll 10
    for (int k = 0; k < KSAMP; k += 2) {
        f4 e0 = __builtin_nontemporal_load(p);
        f4 e1 = __builtin_nontemporal_load(p + n4);
        p += 2 * n4;
        acc0 += e0;
        acc1 += e1;
    }
    f4 sum = acc0 + acc1;

    f4 s = ws[idx];
    f4 m = wm[idx];
    const float invK = 1.0f / (float)KSAMP;

    // softplus(v) = max(v,0) + log1p(exp(-|v|))  (numerically stable)
    f4 sp;
    sp.x = fmaxf(s.x, 0.f) + log1pf(expf(-fabsf(s.x)));
    sp.y = fmaxf(s.y, 0.f) + log1pf(expf(-fabsf(s.y)));
    sp.z = fmaxf(s.z, 0.f) + log1pf(expf(-fabsf(s.z)));
    sp.w = fmaxf(s.w, 0.f) + log1pf(expf(-fabsf(s.w)));

    f4 o;
    o.x = fmaf(sum.x * invK, sp.x, m.x);
    o.y = fmaf(sum.y * invK, sp.y, m.y);
    o.z = fmaf(sum.z * invK, sp.z, m.z);
    o.w = fmaf(sum.w * invK, sp.w, m.w);
    weff[idx] = o;
}

// ---------------------------------------------------------------------------
// Kernel 2: split-K fp32 GEMM, partials to workspace (no atomics).
// 128x128 tile, 256 threads, 8x8 micro-tile, BK=8, KSPLIT=8 -> 512 blocks
// (2 blocks/CU, 2 waves/SIMD). Identical to the 585 µs round-0 structure
// EXCEPT the B-fragment mapping: cols {tx*4..+3} U {64+tx*4..+3} instead of
// {tx*8..+7}. Old mapping: Bs[kk][tx*8] puts lanes tx=0,4,8,12 on the same
// bank quad with distinct addresses -> 4-way LDS conflict (1.58x) on half
// the LDS traffic, and this kernel is LDS-throughput-bound (~3.9k LDS cyc
// vs ~2k VALU cyc per CU-iteration). New mapping: 16B lane stride -> 2-way
// aliasing, which is free (m136). Partial-store indexing updated to match;
// the elementwise reduce kernel is layout-agnostic.
// ---------------------------------------------------------------------------
#define BM 128
#define BN 128
#define BK 8
#define KSPLIT 8

__global__ __launch_bounds__(256, 2) void sgemm_splitk(
    const float* __restrict__ A,   // x      [DB,  DIN]
    const float* __restrict__ B,   // W_eff  [DIN, DOUT]
    float* __restrict__ P)         // partials [KSPLIT][DB][DOUT]
{
    __shared__ float As[BK][BM];   // k-major (A transposed in LDS)
    __shared__ float Bs[BK][BN];

    const int bx = blockIdx.x, by = blockIdx.y, kz = blockIdx.z;
    const int tid = threadIdx.x;
    const int tx = tid & 15;       // 0..15 -> cols {tx*4..+3} and {64+tx*4..+3}
    const int ty = tid >> 4;       // 0..15 -> 8 output rows each

    const int kc = DIN / KSPLIT;   // 128
    const int k_begin = kz * kc;

    // A load map: row = tid>>1 (0..127), kcol = (tid&1)*4
    const int arow = tid >> 1;
    const int acol = (tid & 1) * 4;
    // B load map: krow = tid>>5 (0..7), col = (tid&31)*4
    const int brow = tid >> 5;
    const int bcol = (tid & 31) * 4;

    const float* Aptr = &A[(size_t)(by * BM + arow) * DIN + k_begin + acol];
    const float* Bptr = &B[(size_t)(k_begin + brow) * DOUT + bx * BN + bcol];

    float acc[8][8];
    #pragma unroll
    for (int i = 0; i < 8; ++i)
        #pragma unroll
        for (int j = 0; j < 8; ++j) acc[i][j] = 0.f;

    // Preload first tile
    float4 a = *(const float4*)Aptr;
    float4 b = *(const float4*)Bptr;

    const int niter = kc / BK;     // 16
    for (int it = 0; it < niter; ++it) {
        __syncthreads();           // previous iteration's LDS reads done
        As[acol + 0][arow] = a.x;
        As[acol + 1][arow] = a.y;
        As[acol + 2][arow] = a.z;
        As[acol + 3][arow] = a.w;
        *(float4*)&Bs[brow][bcol] = b;
        __syncthreads();           // tile visible

        // Prefetch next tile while computing this one
        if (it + 1 < niter) {
            a = *(const float4*)(Aptr + (it + 1) * BK);
            b = *(const float4*)(Bptr + (size_t)(it + 1) * BK * DOUT);
        }

        #pragma unroll
        for (int kk = 0; kk < BK; ++kk) {
            float4 a0 = *(const float4*)&As[kk][ty * 8];
            float4 a1 = *(const float4*)&As[kk][ty * 8 + 4];
            float4 b0 = *(const float4*)&Bs[kk][tx * 4];        // 16B lane stride
            float4 b1 = *(const float4*)&Bs[kk][64 + tx * 4];   // -> 2-way (free)
            const float ar[8] = {a0.x, a0.y, a0.z, a0.w, a1.x, a1.y, a1.z, a1.w};
            const float br[8] = {b0.x, b0.y, b0.z, b0.w, b1.x, b1.y, b1.z, b1.w};
            #pragma unroll
            for (int i = 0; i < 8; ++i)
                #pragma unroll
                for (int j = 0; j < 8; ++j)
                    acc[i][j] = fmaf(ar[i], br[j], acc[i][j]);
        }
    }

    // Plain float4 stores to this split's partial buffer (split-column layout)
    float* Pz = P + (size_t)kz * DB * DOUT;
    #pragma unroll
    for (int i = 0; i < 8; ++i) {
        const int r = by * BM + ty * 8 + i;
        float* prow = &Pz[(size_t)r * DOUT + bx * BN];
        *(f4*)&prow[tx * 4]      = (f4){acc[i][0], acc[i][1], acc[i][2], acc[i][3]};
        *(f4*)&prow[64 + tx * 4] = (f4){acc[i][4], acc[i][5], acc[i][6], acc[i][7]};
    }
}

// ---------------------------------------------------------------------------
// Kernel 3: sum the KSPLIT partial buffers into d_out. 1024 blocks -> fully
// parallel, memory-bound (36 MB ~ 6-8 us). Layout-agnostic (elementwise).
// ---------------------------------------------------------------------------
__global__ __launch_bounds__(256) void reduce_kernel(
    const f4* __restrict__ P, f4* __restrict__ out)
{
    const int idx = blockIdx.x * blockDim.x + threadIdx.x;  // 0..262143
    const int n4 = (DB * DOUT) / 4;
    f4 s = P[idx];
    #pragma unroll
    for (int z = 1; z < KSPLIT; ++z) {
        s += P[(size_t)z * n4 + idx];
    }
    out[idx] = s;
}

// ---------------------------------------------------------------------------
extern "C" void kernel_launch(void* const* d_in, const int* in_sizes, int n_in,
                              void* d_out, int out_size, void* d_ws, size_t ws_size,
                              hipStream_t stream) {
    const float* x   = (const float*)d_in[0];   // [1024,1024]
    const float* eps = (const float*)d_in[1];   // [100,1024,1024]
    const float* wm  = (const float*)d_in[2];   // [1024,1024]
    const float* ws  = (const float*)d_in[3];   // [1024,1024]

    float* weff     = (float*)d_ws;                          // 4 MB
    float* partials = (float*)d_ws + (size_t)DIN * DOUT;     // 8 x 4 MB

    weff_kernel<<<(DIN * DOUT / 4) / 256, 256, 0, stream>>>(
        (const f4*)eps, (const f4*)wm, (const f4*)ws, (f4*)weff);

    sgemm_splitk<<<dim3(DOUT / BN, DB / BM, KSPLIT), 256, 0, stream>>>(
        x, weff, partials);

    reduce_kernel<<<(DB * DOUT / 4) / 256, 256, 0, stream>>>(
        (const f4*)partials, (f4*)d_out);
}

// Round 3
// 571.989 us; speedup vs baseline: 1.0992x; 1.0226x over previous
//
#include <hip/hip_runtime.h>
#include <cmath>

// Problem constants: B=1024, IN=1024, OUT=1024, K=100
#define KSAMP 100
#define DIN   1024
#define DOUT  1024
#define DB    1024

typedef float f4    __attribute__((ext_vector_type(4)));
typedef float f32x4 __attribute__((ext_vector_type(4)));
typedef __bf16 bf16x8 __attribute__((ext_vector_type(8)));
typedef unsigned short us4v __attribute__((ext_vector_type(4)));

// fp32 -> bf16 round-to-nearest-even (manual; avoids header dependencies)
static __device__ __forceinline__ unsigned short f2bf(float x) {
    unsigned u = __float_as_uint(x);
    u += 0x7fffu + ((u >> 16) & 1u);
    return (unsigned short)(u >> 16);
}
static __device__ __forceinline__ float bf2f(unsigned short h) {
    return __uint_as_float(((unsigned)h) << 16);
}

// ---------------------------------------------------------------------------
// Kernel 1: stream eps (419 MB), compute W_eff = mean_k(eps)*softplus(ws)+wm.
// Emits W_eff as bf16 hi/lo pair (same 4 MB of writes as fp32 before), and
// also splits x into bf16 hi/lo (adds 8 MB to a 431 MB stream; conversion
// VALU hides under the HBM-bound load loop).
// ---------------------------------------------------------------------------
__global__ __launch_bounds__(256) void weff_kernel(
    const f4* __restrict__ eps,
    const f4* __restrict__ wm,
    const f4* __restrict__ ws,
    const f4* __restrict__ x,
    us4v* __restrict__ wh, us4v* __restrict__ wl,
    us4v* __restrict__ xh, us4v* __restrict__ xl)
{
    const int idx = blockIdx.x * blockDim.x + threadIdx.x;   // 0..262143
    const int n4 = (DIN * DOUT) / 4;

    // x hi/lo split (independent; latency hides under the eps stream)
    {
        f4 xv = x[idx];
        us4v hi, lo;
        hi.x = f2bf(xv.x); lo.x = f2bf(xv.x - bf2f(hi.x));
        hi.y = f2bf(xv.y); lo.y = f2bf(xv.y - bf2f(hi.y));
        hi.z = f2bf(xv.z); lo.z = f2bf(xv.z - bf2f(hi.z));
        hi.w = f2bf(xv.w); lo.w = f2bf(xv.w - bf2f(hi.w));
        xh[idx] = hi; xl[idx] = lo;
    }

    f4 acc0 = {0.f, 0.f, 0.f, 0.f};
    f4 acc1 = {0.f, 0.f, 0.f, 0.f};
    const f4* p = eps + idx;
    #pragma unroll 10
    for (int k = 0; k < KSAMP; k += 2) {
        f4 e0 = __builtin_nontemporal_load(p);
        f4 e1 = __builtin_nontemporal_load(p + n4);
        p += 2 * n4;
        acc0 += e0;
        acc1 += e1;
    }
    f4 sum = acc0 + acc1;

    f4 s = ws[idx];
    f4 m = wm[idx];
    const float invK = 1.0f / (float)KSAMP;

    f4 sp;
    sp.x = fmaxf(s.x, 0.f) + log1pf(expf(-fabsf(s.x)));
    sp.y = fmaxf(s.y, 0.f) + log1pf(expf(-fabsf(s.y)));
    sp.z = fmaxf(s.z, 0.f) + log1pf(expf(-fabsf(s.z)));
    sp.w = fmaxf(s.w, 0.f) + log1pf(expf(-fabsf(s.w)));

    f4 w;
    w.x = fmaf(sum.x * invK, sp.x, m.x);
    w.y = fmaf(sum.y * invK, sp.y, m.y);
    w.z = fmaf(sum.z * invK, sp.z, m.z);
    w.w = fmaf(sum.w * invK, sp.w, m.w);

    us4v hi, lo;
    hi.x = f2bf(w.x); lo.x = f2bf(w.x - bf2f(hi.x));
    hi.y = f2bf(w.y); lo.y = f2bf(w.y - bf2f(hi.y));
    hi.z = f2bf(w.z); lo.z = f2bf(w.z - bf2f(hi.z));
    hi.w = f2bf(w.w); lo.w = f2bf(w.w - bf2f(hi.w));
    wh[idx] = hi; wl[idx] = lo;
}

// ---------------------------------------------------------------------------
// Kernel 2: transpose W_eff hi/lo (ushort [IN][OUT] -> [OUT][IN]) via LDS
// 64x64 tiles. Both global sides fully coalesced (16B/lane). LDS row pad to
// 66 ushorts keeps scatter/readback conflicts at ~2-4 way.
// Purpose: make the GEMM's B operand k-contiguous so MFMA B-fragments are
// single 16B loads (no LDS, no scatter in the hot GEMM).
// ---------------------------------------------------------------------------
__device__ __forceinline__ void transpose_one(
    const unsigned short* __restrict__ S, unsigned short* __restrict__ D,
    unsigned short (*T)[66], int bi, int bj, int t)
{
    const int il = t >> 2;            // 0..63  i within tile
    const int j0 = (t & 3) * 16;      // j start (16 elements per thread)
    const uint4* p = (const uint4*)&S[(size_t)(bi * 64 + il) * DOUT + bj * 64 + j0];
    uint4 v0 = p[0], v1 = p[1];       // 16 ushorts
    unsigned q[8] = {v0.x, v0.y, v0.z, v0.w, v1.x, v1.y, v1.z, v1.w};
    #pragma unroll
    for (int c = 0; c < 8; ++c) {
        T[j0 + 2 * c    ][il] = (unsigned short)(q[c] & 0xffffu);
        T[j0 + 2 * c + 1][il] = (unsigned short)(q[c] >> 16);
    }
    __syncthreads();
    const int ol = t >> 2;            // j within tile (output row)
    const int i0 = (t & 3) * 16;      // i start
    const unsigned* Tp = (const unsigned*)&T[ol][i0];   // 4B-aligned (66*2=132, 2*i0 both %4==0)
    unsigned r[8];
    #pragma unroll
    for (int s2 = 0; s2 < 8; ++s2) r[s2] = Tp[s2];
    uint4 o0 = {r[0], r[1], r[2], r[3]};
    uint4 o1 = {r[4], r[5], r[6], r[7]};
    uint4* dp = (uint4*)&D[(size_t)(bj * 64 + ol) * DIN + bi * 64 + i0];
    dp[0] = o0; dp[1] = o1;
}

__global__ __launch_bounds__(256) void transpose_kernel(
    const unsigned short* __restrict__ Wh, const unsigned short* __restrict__ Wl,
    unsigned short* __restrict__ WTh, unsigned short* __restrict__ WTl)
{
    __shared__ unsigned short T[64][66];
    const int t = threadIdx.x;
    const int bi = blockIdx.y, bj = blockIdx.x;
    transpose_one(Wh, WTh, T, bi, bj, t);
    __syncthreads();
    transpose_one(Wl, WTl, T, bi, bj, t);
}

// ---------------------------------------------------------------------------
// Kernel 3: bf16 hi/lo MFMA GEMM, full K per block (no split-K, no reduce).
// Out = x @ W_eff with 3-product accumulation (hi*hi + hi*lo + lo*hi) -> ~fp32
// accuracy (rel err ~2^-17; abs err ~0.02 on sigma~36 outputs, tol 0.5).
// 256 blocks (1/CU) x 4 waves; each wave owns a 32x32 sub-tile = 2x2 MFMA
// 16x16x32 fragments. Both operands are k-contiguous in global memory
// (x row-major, W pre-transposed) -> every fragment is one 16B load,
// L2-resident (8 MB working set). No LDS, no barriers in the K-loop.
// Fragment maps (m89-verified C/D; standard A/B): A row=l&15, k=8*(l>>4)+j;
// B col=l&15, same k; D col=l&15, row=4*(l>>4)+reg.
// ---------------------------------------------------------------------------
#define MFMA16(a, b, c) __builtin_amdgcn_mfma_f32_16x16x32_bf16((a), (b), (c), 0, 0, 0)

__global__ __launch_bounds__(256) void gemm_mfma(
    const unsigned short* __restrict__ Xh, const unsigned short* __restrict__ Xl,
    const unsigned short* __restrict__ WTh, const unsigned short* __restrict__ WTl,
    float* __restrict__ Out)
{
    const int tid  = threadIdx.x;
    const int lane = tid & 63, wave = tid >> 6;
    const int wr = wave >> 1, wc = wave & 1;
    const int l15 = lane & 15, lq = lane >> 4;
    const int row0 = blockIdx.y * 64 + wr * 32;
    const int col0 = blockIdx.x * 64 + wc * 32;
    const int kq = lq * 8;

    const unsigned short* pa0h = &Xh [(size_t)(row0 + l15)      * DIN + kq];
    const unsigned short* pa1h = &Xh [(size_t)(row0 + 16 + l15) * DIN + kq];
    const unsigned short* pa0l = &Xl [(size_t)(row0 + l15)      * DIN + kq];
    const unsigned short* pa1l = &Xl [(size_t)(row0 + 16 + l15) * DIN + kq];
    const unsigned short* pb0h = &WTh[(size_t)(col0 + l15)      * DIN + kq];
    const unsigned short* pb1h = &WTh[(size_t)(col0 + 16 + l15) * DIN + kq];
    const unsigned short* pb0l = &WTl[(size_t)(col0 + l15)      * DIN + kq];
    const unsigned short* pb1l = &WTl[(size_t)(col0 + 16 + l15) * DIN + kq];

    f32x4 acc00 = {0.f, 0.f, 0.f, 0.f};
    f32x4 acc01 = {0.f, 0.f, 0.f, 0.f};
    f32x4 acc10 = {0.f, 0.f, 0.f, 0.f};
    f32x4 acc11 = {0.f, 0.f, 0.f, 0.f};

    #pragma unroll 4
    for (int k0 = 0; k0 < DIN; k0 += 32) {
        bf16x8 ah0 = *(const bf16x8*)(pa0h + k0);
        bf16x8 ah1 = *(const bf16x8*)(pa1h + k0);
        bf16x8 al0 = *(const bf16x8*)(pa0l + k0);
        bf16x8 al1 = *(const bf16x8*)(pa1l + k0);
        bf16x8 bh0 = *(const bf16x8*)(pb0h + k0);
        bf16x8 bh1 = *(const bf16x8*)(pb1h + k0);
        bf16x8 bl0 = *(const bf16x8*)(pb0l + k0);
        bf16x8 bl1 = *(const bf16x8*)(pb1l + k0);

        acc00 = MFMA16(ah0, bh0, acc00);
        acc01 = MFMA16(ah0, bh1, acc01);
        acc10 = MFMA16(ah1, bh0, acc10);
        acc11 = MFMA16(ah1, bh1, acc11);

        acc00 = MFMA16(ah0, bl0, acc00);
        acc01 = MFMA16(ah0, bl1, acc01);
        acc10 = MFMA16(ah1, bl0, acc10);
        acc11 = MFMA16(ah1, bl1, acc11);

        acc00 = MFMA16(al0, bh0, acc00);
        acc01 = MFMA16(al0, bh1, acc01);
        acc10 = MFMA16(al1, bh0, acc10);
        acc11 = MFMA16(al1, bh1, acc11);
    }

    // D mapping: col = l15, row = lq*4 + r (within each 16x16 fragment).
    #pragma unroll
    for (int r = 0; r < 4; ++r) {
        const size_t ro0 = (size_t)(row0 + lq * 4 + r) * DOUT;
        const size_t ro1 = (size_t)(row0 + 16 + lq * 4 + r) * DOUT;
        Out[ro0 + col0 + l15]      = acc00[r];
        Out[ro0 + col0 + 16 + l15] = acc01[r];
        Out[ro1 + col0 + l15]      = acc10[r];
        Out[ro1 + col0 + 16 + l15] = acc11[r];
    }
}

// ---------------------------------------------------------------------------
extern "C" void kernel_launch(void* const* d_in, const int* in_sizes, int n_in,
                              void* d_out, int out_size, void* d_ws, size_t ws_size,
                              hipStream_t stream) {
    const float* x   = (const float*)d_in[0];   // [1024,1024]
    const float* eps = (const float*)d_in[1];   // [100,1024,1024]
    const float* wm  = (const float*)d_in[2];   // [1024,1024]
    const float* ws  = (const float*)d_in[3];   // [1024,1024]

    // Workspace layout (ushort granules of 1M elements = 2 MB each):
    unsigned short* base = (unsigned short*)d_ws;
    const size_t NE = (size_t)DIN * DOUT;       // 1,048,576
    unsigned short* xh  = base + 0 * NE;
    unsigned short* xl  = base + 1 * NE;
    unsigned short* wh  = base + 2 * NE;
    unsigned short* wl  = base + 3 * NE;
    unsigned short* wth = base + 4 * NE;
    unsigned short* wtl = base + 5 * NE;        // total 12 MB (< prior 36 MB)

    weff_kernel<<<(DIN * DOUT / 4) / 256, 256, 0, stream>>>(
        (const f4*)eps, (const f4*)wm, (const f4*)ws, (const f4*)x,
        (us4v*)wh, (us4v*)wl, (us4v*)xh, (us4v*)xl);

    transpose_kernel<<<dim3(16, 16), 256, 0, stream>>>(wh, wl, wth, wtl);

    gemm_mfma<<<dim3(16, 16), 256, 0, stream>>>(xh, xl, wth, wtl, (float*)d_out);
}